// Round 1
// baseline (177.403 us; speedup 1.0000x reference)
//
#include <hip/hip_runtime.h>
#include <hip/hip_fp16.h>
#include <stdint.h>

// ---- types ----
typedef _Float16 h16;
typedef _Float16 h16x8 __attribute__((ext_vector_type(8)));
typedef float f32x4 __attribute__((ext_vector_type(4)));

// Problem constants
#define BB 4
#define SS 2048
#define DD 1024

__device__ __forceinline__ void gload16(const void* g, void* l) {
    __builtin_amdgcn_global_load_lds(
        (const __attribute__((address_space(1))) uint32_t*)g,
        (__attribute__((address_space(3))) uint32_t*)l, 16, 0, 0);
}

// ---- fp32 -> fp16 convert (8 elems / thread), optional scale ----
__global__ __launch_bounds__(256) void cvt_f32_h16(const float* __restrict__ in,
                                                   h16* __restrict__ out,
                                                   int n8, float scale) {
    int i = blockIdx.x * 256 + threadIdx.x;
    if (i >= n8) return;
    const float4* p = (const float4*)in + (size_t)i * 2;
    float4 a = p[0], b = p[1];
    union { int4 i4; h16 h[8]; } u;
    u.h[0] = (h16)(a.x * scale); u.h[1] = (h16)(a.y * scale);
    u.h[2] = (h16)(a.z * scale); u.h[3] = (h16)(a.w * scale);
    u.h[4] = (h16)(b.x * scale); u.h[5] = (h16)(b.y * scale);
    u.h[6] = (h16)(b.z * scale); u.h[7] = (h16)(b.w * scale);
    ((int4*)out)[i] = u.i4;
}

// ---- bt-form GEMM: C[m][n] = sum_k A[m][k] * B[n][k]  (both row-major along K)
// 128x128 tile, BK=64, 4 waves (2x2), 16x16x32 f16 MFMA, global_load_lds staging.
template<bool F32OUT>
__global__ __launch_bounds__(256) void gemm_bt(
    const h16* __restrict__ A, const h16* __restrict__ B, void* __restrict__ Cv,
    int lda, int ldb, int ldc, int K, int tilesN,
    long long aBatch, long long bBatch, long long cBatch)
{
    __shared__ h16 As[128 * 64];
    __shared__ h16 Bs[128 * 64];

    const int tid = threadIdx.x;
    const int bid = blockIdx.x;
    const int bb  = blockIdx.y;
    const h16* Ab = A + (long long)bb * aBatch;
    const h16* Bb = B + (long long)bb * bBatch;
    const int tm = bid / tilesN, tn = bid % tilesN;
    const int row0 = tm * 128, col0 = tn * 128;

    const int lane = tid & 63, wid = tid >> 6;
    const int wr = (wid >> 1) * 64, wc = (wid & 1) * 64;
    const int frow = lane & 15, fk = (lane >> 4) * 8;

    f32x4 acc[4][4];
#pragma unroll
    for (int m = 0; m < 4; ++m)
#pragma unroll
        for (int n = 0; n < 4; ++n) acc[m][n] = (f32x4){0.f, 0.f, 0.f, 0.f};

    for (int kt = 0; kt < K; kt += 64) {
        // stage A,B tiles: 128 rows x 64 cols fp16 each; 1024 x 16B chunks per tile
#pragma unroll
        for (int i = 0; i < 4; ++i) {
            int j = i * 256 + tid;
            int r = j >> 3;
            int c = (j & 7) * 8;
            gload16(Ab + (size_t)(row0 + r) * lda + kt + c, (void*)(As + (size_t)j * 8));
            gload16(Bb + (size_t)(col0 + r) * ldb + kt + c, (void*)(Bs + (size_t)j * 8));
        }
        __syncthreads();   // compiler drains vmcnt(0) before barrier -> tiles ready
#pragma unroll
        for (int ks = 0; ks < 2; ++ks) {
            h16x8 af[4], bf[4];
#pragma unroll
            for (int m = 0; m < 4; ++m)
                af[m] = *(const h16x8*)(As + (size_t)(wr + m * 16 + frow) * 64 + ks * 32 + fk);
#pragma unroll
            for (int n = 0; n < 4; ++n)
                bf[n] = *(const h16x8*)(Bs + (size_t)(wc + n * 16 + frow) * 64 + ks * 32 + fk);
#pragma unroll
            for (int m = 0; m < 4; ++m)
#pragma unroll
                for (int n = 0; n < 4; ++n)
                    acc[m][n] = __builtin_amdgcn_mfma_f32_16x16x32_f16(af[m], bf[n], acc[m][n], 0, 0, 0);
        }
        __syncthreads();
    }

    // epilogue: C/D layout col=lane&15, row=(lane>>4)*4+reg (m89-verified)
    const int erow = row0 + wr + (lane >> 4) * 4;
    const int ecol = col0 + wc + (lane & 15);
    if (F32OUT) {
        float* C = (float*)Cv + (long long)bb * cBatch;
#pragma unroll
        for (int m = 0; m < 4; ++m)
#pragma unroll
            for (int n = 0; n < 4; ++n)
#pragma unroll
                for (int j = 0; j < 4; ++j)
                    C[(size_t)(erow + m * 16 + j) * ldc + (ecol + n * 16)] = acc[m][n][j];
    } else {
        h16* C = (h16*)Cv + (long long)bb * cBatch;
#pragma unroll
        for (int m = 0; m < 4; ++m)
#pragma unroll
            for (int n = 0; n < 4; ++n)
#pragma unroll
                for (int j = 0; j < 4; ++j)
                    C[(size_t)(erow + m * 16 + j) * ldc + (ecol + n * 16)] = (h16)acc[m][n][j];
    }
}

// ---- row softmax, in place on fp16 rows of length 2048; one block per row ----
__global__ __launch_bounds__(256) void softmax_rows(h16* __restrict__ buf) {
    const int row = blockIdx.x;
    h16* rp = buf + (size_t)row * 2048;
    const int t = threadIdx.x;
    const int lane = t & 63, wid = t >> 6;

    union { int4 i4; h16 h[8]; } u;
    u.i4 = ((const int4*)rp)[t];
    float f[8];
#pragma unroll
    for (int j = 0; j < 8; ++j) f[j] = (float)u.h[j];

    float m = f[0];
#pragma unroll
    for (int j = 1; j < 8; ++j) m = fmaxf(m, f[j]);
#pragma unroll
    for (int off = 32; off; off >>= 1) m = fmaxf(m, __shfl_xor(m, off));

    __shared__ float smax[4];
    __shared__ float ssum[4];
    if (lane == 0) smax[wid] = m;
    __syncthreads();
    m = fmaxf(fmaxf(smax[0], smax[1]), fmaxf(smax[2], smax[3]));

    float s = 0.f;
#pragma unroll
    for (int j = 0; j < 8; ++j) { f[j] = __expf(f[j] - m); s += f[j]; }
#pragma unroll
    for (int off = 32; off; off >>= 1) s += __shfl_xor(s, off);
    if (lane == 0) ssum[wid] = s;
    __syncthreads();
    float inv = 1.0f / (ssum[0] + ssum[1] + ssum[2] + ssum[3]);

#pragma unroll
    for (int j = 0; j < 8; ++j) u.h[j] = (h16)(f[j] * inv);
    ((int4*)rp)[t] = u.i4;
}

extern "C" void kernel_launch(void* const* d_in, const int* in_sizes, int n_in,
                              void* d_out, int out_size, void* d_ws, size_t ws_size,
                              hipStream_t stream) {
    (void)in_sizes; (void)n_in; (void)out_size; (void)ws_size;
    const float* q = (const float*)d_in[0];
    const float* k = (const float*)d_in[1];
    const float* v = (const float*)d_in[2];
    const float* w = (const float*)d_in[3];
    float* out = (float*)d_out;

    const size_t QKV = (size_t)BB * SS * DD;   // 8,388,608 elements
    h16* qh = (h16*)d_ws;            // 16 MB  (reused as vpT after GEMM1)
    h16* kh = qh + QKV;              // 16 MB
    h16* vh = kh + QKV;              // 16 MB
    h16* wh = vh + QKV;              // 2 MB
    h16* sc = wh + (size_t)DD * DD;  // scores / P: B*S*S fp16 = 33.5 MB
    // total ws use: 86 MB

    // 1) fp32 -> fp16 conversions (scale 1/sqrt(64) folded into q; exact pow2)
    cvt_f32_h16<<<(int)(QKV / 8 + 255) / 256, 256, 0, stream>>>(q, qh, (int)(QKV / 8), 0.125f);
    cvt_f32_h16<<<(int)(QKV / 8 + 255) / 256, 256, 0, stream>>>(k, kh, (int)(QKV / 8), 1.0f);
    cvt_f32_h16<<<(int)(QKV / 8 + 255) / 256, 256, 0, stream>>>(v, vh, (int)(QKV / 8), 1.0f);
    cvt_f32_h16<<<(DD * DD / 8 + 255) / 256, 256, 0, stream>>>(w, wh, DD * DD / 8, 1.0f);

    // 2) GEMM1: scores[b][q][k] = sum_d qh[b,q,d]*kh[b,k,d]; M=N=2048, K=1024 per batch
    gemm_bt<false><<<dim3((SS / 128) * (SS / 128), BB), 256, 0, stream>>>(
        qh, kh, (void*)sc, DD, DD, SS, DD, SS / 128,
        (long long)SS * DD, (long long)SS * DD, (long long)SS * SS);

    // 3) softmax rows in place (fp16 -> fp16 P)
    softmax_rows<<<BB * SS, 256, 0, stream>>>(sc);

    // 4) GEMM2: vpT[e][s] = sum_d W[e,d] * V[s,d]; M=1024(e), N=8192(s), K=1024
    h16* vpT = qh;  // reuse q region
    gemm_bt<false><<<dim3((DD / 128) * ((BB * SS) / 128), 1), 256, 0, stream>>>(
        wh, vh, (void*)vpT, DD, DD, BB * SS, DD, (BB * SS) / 128,
        0LL, 0LL, 0LL);

    // 5) GEMM3: Y[b][q][e] = sum_k P[b,q,k] * vpT[e, b*2048+k]; M=2048, N=1024, K=2048
    gemm_bt<true><<<dim3((SS / 128) * (DD / 128), BB), 256, 0, stream>>>(
        sc, vpT, (void*)out, SS, BB * SS, DD, SS, DD / 128,
        (long long)SS * SS, (long long)SS, (long long)SS * DD);
}

// Round 2
// 156.370 us; speedup vs baseline: 1.1345x; 1.1345x over previous
//
#include <hip/hip_runtime.h>
#include <hip/hip_fp16.h>
#include <stdint.h>

// ---- types ----
typedef _Float16 h16;
typedef _Float16 h16x8 __attribute__((ext_vector_type(8)));
typedef float f32x4 __attribute__((ext_vector_type(4)));

#define BB 4
#define SS 2048
#define DD 1024

__device__ __forceinline__ void gload16(const void* g, void* l) {
    __builtin_amdgcn_global_load_lds(
        (const __attribute__((address_space(1))) uint32_t*)g,
        (__attribute__((address_space(3))) uint32_t*)l, 16, 0, 0);
}

// ---- fp32 -> fp16 convert (8 elems / thread), optional scale ----
__global__ __launch_bounds__(256) void cvt_f32_h16(const float* __restrict__ in,
                                                   h16* __restrict__ out,
                                                   int n8, float scale) {
    int i = blockIdx.x * 256 + threadIdx.x;
    if (i >= n8) return;
    const float4* p = (const float4*)in + (size_t)i * 2;
    float4 a = p[0], b = p[1];
    union { int4 i4; h16 h[8]; } u;
    u.h[0] = (h16)(a.x * scale); u.h[1] = (h16)(a.y * scale);
    u.h[2] = (h16)(a.z * scale); u.h[3] = (h16)(a.w * scale);
    u.h[4] = (h16)(b.x * scale); u.h[5] = (h16)(b.y * scale);
    u.h[6] = (h16)(b.z * scale); u.h[7] = (h16)(b.w * scale);
    ((int4*)out)[i] = u.i4;
}

// ---- bt-form GEMM: C[m][n] = sum_k A[m][k] * B[n][k]
// BM=128, BN=256, BK=64. 8 waves (2M x 4N), per-wave 64x64 output.
// 3-buffer LDS pipeline (48KB/buf = 144KB), prefetch depth 2 K-tiles,
// counted s_waitcnt vmcnt(6) at iteration boundary (never 0 except tail).
// T2 XOR-swizzle: LDS granule g holds global granule g^(row&7); ds_read uses same XOR.
#define SLOTS_A 1024              // 128 rows * 8 granules
#define SLOTS_T 3072              // A(1024) + B(2048) slots of 16B

template<bool F32OUT>
__global__ __launch_bounds__(512, 2) void gemm_bt(
    const h16* __restrict__ A, const h16* __restrict__ B, void* __restrict__ Cv,
    int lda, int ldb, int ldc, int K, int tilesN, int tilesMN,
    long long aBatch, long long bBatch, long long cBatch)
{
    __shared__ h16 lds[3 * SLOTS_T * 8];   // 144 KB

    const int tid = threadIdx.x;
    // bijective XCD swizzle (gridDim.x % 8 == 0 for all our launches)
    const int nwg = gridDim.x;
    const int bid = blockIdx.x;
    const int wgid = (bid & 7) * (nwg >> 3) + (bid >> 3);
    const int bb  = wgid / tilesMN;
    const int rem = wgid % tilesMN;
    const int tm = rem / tilesN, tn = rem % tilesN;
    const int row0 = tm * 128, col0 = tn * 256;

    const h16* Ab = A + (long long)bb * aBatch;
    const h16* Bb = B + (long long)bb * bBatch;

    const int lane = tid & 63, wid = tid >> 6;
    const int wm = wid >> 2, wn = wid & 3;       // 2M x 4N waves
    const int frow = lane & 15;
    const int kq = lane >> 4;                     // 0..3 (k-granule within 32)
    const int xr = frow & 7;                      // read-side swizzle key

    // staging: thread covers LDS slot j = round*512 + tid; row r = j>>3, granule g = j&7.
    // slot holds global granule g ^ (r&7)  -> src col offset constant per thread:
    const int sg = (((tid & 7) ^ ((tid >> 3) & 7)) * 8);
    const int sr = tid >> 3;                      // row within 64-row round

    const int NT = K >> 6;

    f32x4 acc[4][4];
#pragma unroll
    for (int m = 0; m < 4; ++m)
#pragma unroll
        for (int n = 0; n < 4; ++n) acc[m][n] = (f32x4){0.f, 0.f, 0.f, 0.f};

    auto STAGE = [&](int kt, int buf) {
        const h16* as = Ab + (size_t)(row0 + sr) * lda + kt + sg;
        const h16* bs = Bb + (size_t)(col0 + sr) * ldb + kt + sg;
        h16* la = lds + ((size_t)buf * SLOTS_T + tid) * 8;
        h16* lb = lds + ((size_t)buf * SLOTS_T + SLOTS_A + tid) * 8;
#pragma unroll
        for (int i = 0; i < 2; ++i)             // A: 128x64 = 2 rounds
            gload16(as + (size_t)i * 64 * lda, la + (size_t)i * 512 * 8);
#pragma unroll
        for (int i = 0; i < 4; ++i)             // B: 256x64 = 4 rounds
            gload16(bs + (size_t)i * 64 * ldb, lb + (size_t)i * 512 * 8);
    };

    // ---- prologue: stage tiles 0,1; wait tile 0 (leave tile 1 in flight) ----
    STAGE(0, 0);
    STAGE(64, 1);
    asm volatile("s_waitcnt vmcnt(6)" ::: "memory");
    __builtin_amdgcn_s_barrier();
    __builtin_amdgcn_sched_barrier(0);

    int cur = 0;
    for (int t = 0; t < NT; ++t) {
        if (t + 2 < NT) STAGE((t + 2) << 6, (cur == 0) ? 2 : cur - 1);  // (t+2)%3
        const h16* bufp = lds + (size_t)cur * (SLOTS_T * 8);
#pragma unroll
        for (int ks = 0; ks < 2; ++ks) {
            const int g8 = (((kq + 4 * ks) ^ xr) * 8);
            h16x8 af[4], bf[4];
#pragma unroll
            for (int m = 0; m < 4; ++m)
                af[m] = *(const h16x8*)(bufp + (wm * 64 + m * 16 + frow) * 64 + g8);
#pragma unroll
            for (int n = 0; n < 4; ++n)
                bf[n] = *(const h16x8*)(bufp + SLOTS_A * 8 + (wn * 64 + n * 16 + frow) * 64 + g8);
            __builtin_amdgcn_s_setprio(1);
#pragma unroll
            for (int m = 0; m < 4; ++m)
#pragma unroll
                for (int n = 0; n < 4; ++n)
                    acc[m][n] = __builtin_amdgcn_mfma_f32_16x16x32_f16(af[m], bf[n], acc[m][n], 0, 0, 0);
            __builtin_amdgcn_s_setprio(0);
        }
        if (t == NT - 1) break;
        // boundary: tile t+1 must be resident (issued at iter t-1); tile t+2's 6 loads stay in flight
        if (t + 2 < NT) asm volatile("s_waitcnt vmcnt(6) lgkmcnt(0)" ::: "memory");
        else            asm volatile("s_waitcnt vmcnt(0) lgkmcnt(0)" ::: "memory");
        __builtin_amdgcn_s_barrier();
        __builtin_amdgcn_sched_barrier(0);
        cur = (cur == 2) ? 0 : cur + 1;
    }

    // ---- epilogue: C/D layout col=lane&15, row=(lane>>4)*4+reg ----
    const int erow = row0 + wm * 64 + (lane >> 4) * 4;
    const int ecol = col0 + wn * 64 + (lane & 15);
    if (F32OUT) {
        float* C = (float*)Cv + (long long)bb * cBatch;
#pragma unroll
        for (int m = 0; m < 4; ++m)
#pragma unroll
            for (int n = 0; n < 4; ++n)
#pragma unroll
                for (int j = 0; j < 4; ++j)
                    C[(size_t)(erow + m * 16 + j) * ldc + (ecol + n * 16)] = acc[m][n][j];
    } else {
        h16* C = (h16*)Cv + (long long)bb * cBatch;
#pragma unroll
        for (int m = 0; m < 4; ++m)
#pragma unroll
            for (int n = 0; n < 4; ++n)
#pragma unroll
                for (int j = 0; j < 4; ++j)
                    C[(size_t)(erow + m * 16 + j) * ldc + (ecol + n * 16)] = (h16)acc[m][n][j];
    }
}

// ---- row softmax, in place on fp16 rows of length 2048; one block per row ----
__global__ __launch_bounds__(256) void softmax_rows(h16* __restrict__ buf) {
    const int row = blockIdx.x;
    h16* rp = buf + (size_t)row * 2048;
    const int t = threadIdx.x;
    const int lane = t & 63, wid = t >> 6;

    union { int4 i4; h16 h[8]; } u;
    u.i4 = ((const int4*)rp)[t];
    float f[8];
#pragma unroll
    for (int j = 0; j < 8; ++j) f[j] = (float)u.h[j];

    float m = f[0];
#pragma unroll
    for (int j = 1; j < 8; ++j) m = fmaxf(m, f[j]);
#pragma unroll
    for (int off = 32; off; off >>= 1) m = fmaxf(m, __shfl_xor(m, off));

    __shared__ float smax[4];
    __shared__ float ssum[4];
    if (lane == 0) smax[wid] = m;
    __syncthreads();
    m = fmaxf(fmaxf(smax[0], smax[1]), fmaxf(smax[2], smax[3]));

    float s = 0.f;
#pragma unroll
    for (int j = 0; j < 8; ++j) { f[j] = __expf(f[j] - m); s += f[j]; }
#pragma unroll
    for (int off = 32; off; off >>= 1) s += __shfl_xor(s, off);
    if (lane == 0) ssum[wid] = s;
    __syncthreads();
    float inv = 1.0f / (ssum[0] + ssum[1] + ssum[2] + ssum[3]);

#pragma unroll
    for (int j = 0; j < 8; ++j) u.h[j] = (h16)(f[j] * inv);
    ((int4*)rp)[t] = u.i4;
}

extern "C" void kernel_launch(void* const* d_in, const int* in_sizes, int n_in,
                              void* d_out, int out_size, void* d_ws, size_t ws_size,
                              hipStream_t stream) {
    (void)in_sizes; (void)n_in; (void)out_size; (void)ws_size;
    const float* q = (const float*)d_in[0];
    const float* k = (const float*)d_in[1];
    const float* v = (const float*)d_in[2];
    const float* w = (const float*)d_in[3];
    float* out = (float*)d_out;

    const size_t QKV = (size_t)BB * SS * DD;
    h16* qh = (h16*)d_ws;            // 16 MB (reused as vpT after GEMM1 consumes q)
    h16* kh = qh + QKV;              // 16 MB
    h16* vh = kh + QKV;              // 16 MB
    h16* wh = vh + QKV;              // 2 MB
    h16* sc = wh + (size_t)DD * DD;  // scores / P: 33.5 MB

    // 1) fp32 -> fp16 (scale 1/sqrt(64)=0.125 folded into q)
    cvt_f32_h16<<<(int)(QKV / 8 + 255) / 256, 256, 0, stream>>>(q, qh, (int)(QKV / 8), 0.125f);
    cvt_f32_h16<<<(int)(QKV / 8 + 255) / 256, 256, 0, stream>>>(k, kh, (int)(QKV / 8), 1.0f);
    cvt_f32_h16<<<(int)(QKV / 8 + 255) / 256, 256, 0, stream>>>(v, vh, (int)(QKV / 8), 1.0f);
    cvt_f32_h16<<<(DD * DD / 8 + 255) / 256, 256, 0, stream>>>(w, wh, DD * DD / 8, 1.0f);

    // 2) GEMM1: scores[b][q][k], M=2048 N=2048 K=1024 per batch
    //    tilesM=16, tilesN=8 -> 128 tiles * 4 batches = 512 wgs
    gemm_bt<false><<<512, 512, 0, stream>>>(
        qh, kh, (void*)sc, DD, DD, SS, DD, /*tilesN=*/8, /*tilesMN=*/128,
        (long long)SS * DD, (long long)SS * DD, (long long)SS * SS);

    // 3) softmax rows in place
    softmax_rows<<<BB * SS, 256, 0, stream>>>(sc);

    // 4) GEMM2: vpT[e][s] = sum_d W[e,d]*V[s,d]; M=1024 N=8192 K=1024
    //    tilesM=8, tilesN=32 -> 256 wgs
    h16* vpT = qh;
    gemm_bt<false><<<256, 512, 0, stream>>>(
        wh, vh, (void*)vpT, DD, DD, BB * SS, DD, /*tilesN=*/32, /*tilesMN=*/256,
        0LL, 0LL, 0LL);

    // 5) GEMM3: Y[b][q][e] = sum_k P[b,q,k]*vpT[e, b*2048+k]; M=2048 N=1024 K=2048
    //    tilesM=16, tilesN=4 -> 64 tiles * 4 batches = 256 wgs
    gemm_bt<true><<<256, 512, 0, stream>>>(
        sc, vpT, (void*)out, SS, BB * SS, DD, SS, /*tilesN=*/4, /*tilesMN=*/64,
        (long long)SS * SS, (long long)SS, (long long)SS * DD);
}

// Round 3
// 150.858 us; speedup vs baseline: 1.1760x; 1.0365x over previous
//
#include <hip/hip_runtime.h>
#include <hip/hip_fp16.h>
#include <stdint.h>

// ---- types ----
typedef _Float16 h16;
typedef _Float16 h16x8 __attribute__((ext_vector_type(8)));
typedef float f32x4 __attribute__((ext_vector_type(4)));

#define BB 4
#define SS 2048
#define DD 1024

__device__ __forceinline__ void gload16(const void* g, void* l) {
    __builtin_amdgcn_global_load_lds(
        (const __attribute__((address_space(1))) uint32_t*)g,
        (__attribute__((address_space(3))) uint32_t*)l, 16, 0, 0);
}

// ---- fp32 -> fp16 convert (8 elems / thread), optional scale ----
__global__ __launch_bounds__(256) void cvt_f32_h16(const float* __restrict__ in,
                                                   h16* __restrict__ out,
                                                   int n8, float scale) {
    int i = blockIdx.x * 256 + threadIdx.x;
    if (i >= n8) return;
    const float4* p = (const float4*)in + (size_t)i * 2;
    float4 a = p[0], b = p[1];
    union { int4 i4; h16 h[8]; } u;
    u.h[0] = (h16)(a.x * scale); u.h[1] = (h16)(a.y * scale);
    u.h[2] = (h16)(a.z * scale); u.h[3] = (h16)(a.w * scale);
    u.h[4] = (h16)(b.x * scale); u.h[5] = (h16)(b.y * scale);
    u.h[6] = (h16)(b.z * scale); u.h[7] = (h16)(b.w * scale);
    ((int4*)out)[i] = u.i4;
}

// ==== 8-phase bt-form GEMM: C[m][n] = sum_k A[m][k]*B[n][k] ====
// BN=256 fixed, BM in {256,128}. BK=64, 512 threads = 8 waves (2M x 4N).
// Per-wave C: (BM/2) x 64.  4 phases per K-tile (quadrants), 2 K-tiles of LDS.
// Ledger: group G stages {A_mh1(G+1)@p0, A_mh0(G+2)@p1, B_nh0(G+2)@p2,
// B_nh1(G+2)@p3}; boundary s_waitcnt vmcnt(VB) once per K-tile (VB=6 or 5).
// T2 granule swizzle: slot s holds global granule s^(r&7) (both-sides, rule 21).
template<int BM, bool F32OUT>
__global__ __launch_bounds__(512, 2) void gemm8p(
    const h16* __restrict__ A, const h16* __restrict__ B, void* __restrict__ Cv,
    int lda, int ldb, int ldc, int K, int tilesN, int tilesMN,
    long long aBatch, long long bBatch, long long cBatch)
{
    constexpr int WROWS  = BM / 2;        // per-wave rows: 128 or 64
    constexpr int MF     = WROWS / 16;    // m-frags per wave: 8 or 4
    constexpr int MQ     = MF / 2;        // m-frags per quadrant: 4 or 2
    constexpr int AH     = WROWS / 2;     // A-half run length: 64 or 32
    constexpr int ALOADS = BM / 128;      // gloads/thread per A-half: 2 or 1
    constexpr int ABYTES = BM * 128;
    constexpr int BBYTES = 256 * 128;
    constexpr int BUFB   = ABYTES + BBYTES;

    __shared__ __align__(1024) char lds[2 * BUFB];

    const int tid = threadIdx.x;
    const int nwg = gridDim.x;            // always %8==0 here
    const int bid = blockIdx.x;
    const int wgid = (bid & 7) * (nwg >> 3) + (bid >> 3);   // XCD swizzle
    const int bb  = wgid / tilesMN;
    const int rem = wgid % tilesMN;
    const int tm = rem / tilesN, tn = rem % tilesN;
    const int row0 = tm * BM, col0 = tn * 256;

    const h16* Ab = A + (long long)bb * aBatch;
    const h16* Bb = B + (long long)bb * bBatch;

    const int lane = tid & 63, wid = tid >> 6;
    const int wm = wid >> 2, wn = wid & 3;     // 2M x 4N
    const int frow = lane & 15, kq = lane >> 4;

    const int NT = K >> 6;

    f32x4 acc[MF][4];
#pragma unroll
    for (int m = 0; m < MF; ++m)
#pragma unroll
        for (int n = 0; n < 4; ++n) acc[m][n] = (f32x4){0.f, 0.f, 0.f, 0.f};

    char* l0 = (char*)lds;

    auto STAGE_A = [&](int kt, int buf, int mh) {
#pragma unroll
        for (int i = 0; i < ALOADS; ++i) {
            int d = wid * (ALOADS * 64) + i * 64 + lane;
            int s = d & 7, hr = d >> 3;
            int r = ((hr & ~(AH - 1)) << 1) + mh * AH + (hr & (AH - 1));
            int gg = s ^ (r & 7);
            gload16(Ab + (size_t)(row0 + r) * lda + kt + gg * 8,
                    l0 + buf * BUFB + (r * 8 + s) * 16);
        }
    };
    auto STAGE_B = [&](int kt, int buf, int nh) {
#pragma unroll
        for (int i = 0; i < 2; ++i) {
            int d = wid * 128 + i * 64 + lane;
            int s = d & 7, hr = d >> 3;
            int r = ((hr & ~31) << 1) + nh * 32 + (hr & 31);
            int gg = s ^ (r & 7);
            gload16(Bb + (size_t)(col0 + r) * ldb + kt + gg * 8,
                    l0 + buf * BUFB + ABYTES + (r * 8 + s) * 16);
        }
    };
    auto READ_A = [&](int buf, int mh, h16x8 (&af)[MQ][2]) {
#pragma unroll
        for (int mm = 0; mm < MQ; ++mm)
#pragma unroll
            for (int ks = 0; ks < 2; ++ks) {
                int r = wm * WROWS + (mh * MQ + mm) * 16 + frow;
                int s = (ks * 4 + kq) ^ (r & 7);
                af[mm][ks] = *(const h16x8*)(l0 + buf * BUFB + (r * 8 + s) * 16);
            }
    };
    auto READ_B = [&](int buf, int nh, h16x8 (&bf)[2][2]) {
#pragma unroll
        for (int nn = 0; nn < 2; ++nn)
#pragma unroll
            for (int ks = 0; ks < 2; ++ks) {
                int r = wn * 64 + (nh * 2 + nn) * 16 + frow;
                int s = (ks * 4 + kq) ^ (r & 7);
                bf[nn][ks] = *(const h16x8*)(l0 + buf * BUFB + ABYTES + (r * 8 + s) * 16);
            }
    };
    auto MFMA_Q = [&](int mh, int nh, h16x8 (&af)[MQ][2], h16x8 (&bf)[2][2]) {
        __builtin_amdgcn_s_setprio(1);
#pragma unroll
        for (int mm = 0; mm < MQ; ++mm)
#pragma unroll
            for (int nn = 0; nn < 2; ++nn)
#pragma unroll
                for (int ks = 0; ks < 2; ++ks)
                    acc[mh * MQ + mm][nh * 2 + nn] =
                        __builtin_amdgcn_mfma_f32_16x16x32_f16(
                            af[mm][ks], bf[nn][ks], acc[mh * MQ + mm][nh * 2 + nn], 0, 0, 0);
        __builtin_amdgcn_s_setprio(0);
    };
    auto WAIT_LGKM_PIN = [&]() {
        asm volatile("s_waitcnt lgkmcnt(0)" ::: "memory");
        __builtin_amdgcn_sched_barrier(0);
    };

    // ---- prologue: K0 fully + K1 {A_mh0, B_nh0, B_nh1} (A_mh1(K1) staged in G0 p0)
    STAGE_A(0, 0, 0); STAGE_B(0, 0, 0); STAGE_B(0, 0, 1); STAGE_A(0, 0, 1);
    STAGE_A(64, 1, 0); STAGE_B(64, 1, 0); STAGE_B(64, 1, 1);
    if constexpr (BM == 256) asm volatile("s_waitcnt vmcnt(6)" ::: "memory");
    else                     asm volatile("s_waitcnt vmcnt(5)" ::: "memory");
    __builtin_amdgcn_s_barrier();

    h16x8 af[MQ][2], bf0[2][2], bf1[2][2];

    for (int G = 0; G < NT; ++G) {
        const int buf = G & 1;
        const int kt1 = (G + 1) << 6, kt2 = (G + 2) << 6;
        // ---- p0: quadrant (0,0); stage A_mh1(G+1)
        READ_A(buf, 0, af);
        READ_B(buf, 0, bf0);
        if (G + 1 < NT) STAGE_A(kt1, buf ^ 1, 1);
        __builtin_amdgcn_s_barrier();
        WAIT_LGKM_PIN();
        MFMA_Q(0, 0, af, bf0);
        __builtin_amdgcn_sched_barrier(0);
        __builtin_amdgcn_s_barrier();
        // ---- p1: quadrant (0,1); stage A_mh0(G+2)
        READ_B(buf, 1, bf1);
        if (G + 2 < NT) STAGE_A(kt2, buf, 0);
        __builtin_amdgcn_s_barrier();
        WAIT_LGKM_PIN();
        MFMA_Q(0, 1, af, bf1);
        __builtin_amdgcn_sched_barrier(0);
        __builtin_amdgcn_s_barrier();
        // ---- p2: quadrant (1,0); stage B_nh0(G+2); bf0 reused from p0
        READ_A(buf, 1, af);
        if (G + 2 < NT) STAGE_B(kt2, buf, 0);
        __builtin_amdgcn_s_barrier();
        WAIT_LGKM_PIN();
        MFMA_Q(1, 0, af, bf0);
        __builtin_amdgcn_sched_barrier(0);
        __builtin_amdgcn_s_barrier();
        // ---- p3: quadrant (1,1); stage B_nh1(G+2); no ds_reads
        if (G + 2 < NT) STAGE_B(kt2, buf, 1);
        __builtin_amdgcn_s_barrier();
        WAIT_LGKM_PIN();
        MFMA_Q(1, 1, af, bf1);
        __builtin_amdgcn_sched_barrier(0);
        // ---- K-tile boundary: counted vmcnt (never 0 except tail)
        if (G + 2 >= NT) {
            asm volatile("s_waitcnt vmcnt(0)" ::: "memory");
        } else if constexpr (BM == 256) {
            asm volatile("s_waitcnt vmcnt(6)" ::: "memory");
        } else {
            asm volatile("s_waitcnt vmcnt(5)" ::: "memory");
        }
        __builtin_amdgcn_s_barrier();
    }

    // ---- epilogue: C/D layout col=lane&15, row=(lane>>4)*4+j
    const int erow = row0 + wm * WROWS + (lane >> 4) * 4;
    const int ecol = col0 + wn * 64 + (lane & 15);
    if (F32OUT) {
        float* C = (float*)Cv + (long long)bb * cBatch;
#pragma unroll
        for (int m = 0; m < MF; ++m)
#pragma unroll
            for (int n = 0; n < 4; ++n)
#pragma unroll
                for (int j = 0; j < 4; ++j)
                    C[(size_t)(erow + m * 16 + j) * ldc + (ecol + n * 16)] = acc[m][n][j];
    } else {
        h16* C = (h16*)Cv + (long long)bb * cBatch;
#pragma unroll
        for (int m = 0; m < MF; ++m)
#pragma unroll
            for (int n = 0; n < 4; ++n)
#pragma unroll
                for (int j = 0; j < 4; ++j)
                    C[(size_t)(erow + m * 16 + j) * ldc + (ecol + n * 16)] = (h16)acc[m][n][j];
    }
}

// ---- row softmax, in place on fp16 rows of length 2048; one block per row ----
__global__ __launch_bounds__(256) void softmax_rows(h16* __restrict__ buf) {
    const int row = blockIdx.x;
    h16* rp = buf + (size_t)row * 2048;
    const int t = threadIdx.x;
    const int lane = t & 63, wid = t >> 6;

    union { int4 i4; h16 h[8]; } u;
    u.i4 = ((const int4*)rp)[t];
    float f[8];
#pragma unroll
    for (int j = 0; j < 8; ++j) f[j] = (float)u.h[j];

    float m = f[0];
#pragma unroll
    for (int j = 1; j < 8; ++j) m = fmaxf(m, f[j]);
#pragma unroll
    for (int off = 32; off; off >>= 1) m = fmaxf(m, __shfl_xor(m, off));

    __shared__ float smax[4];
    __shared__ float ssum[4];
    if (lane == 0) smax[wid] = m;
    __syncthreads();
    m = fmaxf(fmaxf(smax[0], smax[1]), fmaxf(smax[2], smax[3]));

    float s = 0.f;
#pragma unroll
    for (int j = 0; j < 8; ++j) { f[j] = __expf(f[j] - m); s += f[j]; }
#pragma unroll
    for (int off = 32; off; off >>= 1) s += __shfl_xor(s, off);
    if (lane == 0) ssum[wid] = s;
    __syncthreads();
    float inv = 1.0f / (ssum[0] + ssum[1] + ssum[2] + ssum[3]);

#pragma unroll
    for (int j = 0; j < 8; ++j) u.h[j] = (h16)(f[j] * inv);
    ((int4*)rp)[t] = u.i4;
}

extern "C" void kernel_launch(void* const* d_in, const int* in_sizes, int n_in,
                              void* d_out, int out_size, void* d_ws, size_t ws_size,
                              hipStream_t stream) {
    (void)in_sizes; (void)n_in; (void)out_size; (void)ws_size;
    const float* q = (const float*)d_in[0];
    const float* k = (const float*)d_in[1];
    const float* v = (const float*)d_in[2];
    const float* w = (const float*)d_in[3];
    float* out = (float*)d_out;

    const size_t QKV = (size_t)BB * SS * DD;
    h16* qh = (h16*)d_ws;            // 16 MB (reused as vpT after GEMM1 consumes q)
    h16* kh = qh + QKV;              // 16 MB
    h16* vh = kh + QKV;              // 16 MB
    h16* wh = vh + QKV;              // 2 MB
    h16* sc = wh + (size_t)DD * DD;  // scores / P: 33.5 MB

    // 1) fp32 -> fp16 (scale 1/sqrt(64)=0.125 folded into q)
    cvt_f32_h16<<<(int)(QKV / 8 + 255) / 256, 256, 0, stream>>>(q, qh, (int)(QKV / 8), 0.125f);
    cvt_f32_h16<<<(int)(QKV / 8 + 255) / 256, 256, 0, stream>>>(k, kh, (int)(QKV / 8), 1.0f);
    cvt_f32_h16<<<(int)(QKV / 8 + 255) / 256, 256, 0, stream>>>(v, vh, (int)(QKV / 8), 1.0f);
    cvt_f32_h16<<<(DD * DD / 8 + 255) / 256, 256, 0, stream>>>(w, wh, DD * DD / 8, 1.0f);

    // 2) GEMM1: scores[b][q][k]; M=N=2048, K=1024 per batch. 256x256 tiles:
    //    8x8=64 tiles x 4 batches = 256 wgs (1/CU exact)
    gemm8p<256, false><<<256, 512, 0, stream>>>(
        qh, kh, (void*)sc, DD, DD, SS, DD, /*tilesN=*/8, /*tilesMN=*/64,
        (long long)SS * DD, (long long)SS * DD, (long long)SS * SS);

    // 3) softmax rows in place
    softmax_rows<<<BB * SS, 256, 0, stream>>>(sc);

    // 4) GEMM2: vpT[e][s] = sum_d W[e,d]*V[s,d]; M=1024, N=8192, K=1024.
    //    128x256 tiles: 8x32 = 256 wgs
    h16* vpT = qh;
    gemm8p<128, false><<<256, 512, 0, stream>>>(
        wh, vh, (void*)vpT, DD, DD, BB * SS, DD, /*tilesN=*/32, /*tilesMN=*/256,
        0LL, 0LL, 0LL);

    // 5) GEMM3: Y[b][q][e] = sum_k P[b,q,k]*vpT[e, b*2048+k]; M=2048/batch, N=1024, K=2048.
    //    128x256 tiles: 16x4=64 x 4 batches = 256 wgs
    gemm8p<128, true><<<256, 512, 0, stream>>>(
        sc, vpT, (void*)out, SS, BB * SS, DD, SS, /*tilesN=*/4, /*tilesMN=*/64,
        (long long)SS * SS, (long long)SS, (long long)SS * DD);
}

// Round 4
// 149.036 us; speedup vs baseline: 1.1903x; 1.0122x over previous
//
#include <hip/hip_runtime.h>
#include <hip/hip_fp16.h>
#include <stdint.h>

// ---- types ----
typedef _Float16 h16;
typedef _Float16 h16x8 __attribute__((ext_vector_type(8)));
typedef float f32x4 __attribute__((ext_vector_type(4)));

#define BB 4
#define SS 2048
#define DD 1024

__device__ __forceinline__ void gload16(const void* g, void* l) {
    __builtin_amdgcn_global_load_lds(
        (const __attribute__((address_space(1))) uint32_t*)g,
        (__attribute__((address_space(3))) uint32_t*)l, 16, 0, 0);
}

// ---- fp32 -> fp16 convert (8 elems / thread), optional scale ----
__global__ __launch_bounds__(256) void cvt_f32_h16(const float* __restrict__ in,
                                                   h16* __restrict__ out,
                                                   int n8, float scale) {
    int i = blockIdx.x * 256 + threadIdx.x;
    if (i >= n8) return;
    const float4* p = (const float4*)in + (size_t)i * 2;
    float4 a = p[0], b = p[1];
    union { int4 i4; h16 h[8]; } u;
    u.h[0] = (h16)(a.x * scale); u.h[1] = (h16)(a.y * scale);
    u.h[2] = (h16)(a.z * scale); u.h[3] = (h16)(a.w * scale);
    u.h[4] = (h16)(b.x * scale); u.h[5] = (h16)(b.y * scale);
    u.h[6] = (h16)(b.z * scale); u.h[7] = (h16)(b.w * scale);
    ((int4*)out)[i] = u.i4;
}

// ==== 8-phase bt-form GEMM: C[m][n] = sum_k A[m][k]*B[n][k] ====
// BN=256 fixed, BM in {256,128}. BK=64, 512 threads = 8 waves (2M x 4N).
// 4 phases per K-tile (C-quadrants), double-buffered LDS (2 K-tiles).
// Ledger: iter G stages {A_mh1(G+1)@p0, A_mh0(G+2)@p1, B_nh0(G+2)@p2,
// B_nh1(G+2)@p3}; boundary s_waitcnt vmcnt(VB) once per K-tile (VB=6 or 5).
// T2 granule swizzle: slot s holds global granule s^(r&7) (both-sides, rule 21).
// NOTE: no lgkmcnt(0)/sched_barrier pins — compiler emits fine-grained lgkmcnt
// so ds_read latency drains UNDER the MFMA cluster (m141 lesson).
template<int BM, bool F32OUT>
__global__ __launch_bounds__(512, 2) void gemm8p(
    const h16* __restrict__ A, const h16* __restrict__ B, void* __restrict__ Cv,
    int lda, int ldb, int ldc, int K, int tilesN, int tilesMN,
    long long aBatch, long long bBatch, long long cBatch)
{
    constexpr int WROWS  = BM / 2;        // per-wave rows: 128 or 64
    constexpr int MF     = WROWS / 16;    // m-frags per wave: 8 or 4
    constexpr int MQ     = MF / 2;        // m-frags per quadrant: 4 or 2
    constexpr int AH     = WROWS / 2;     // A-half run length: 64 or 32
    constexpr int ALOADS = BM / 128;      // gloads/thread per A-half: 2 or 1
    constexpr int ABYTES = BM * 128;
    constexpr int BBYTES = 256 * 128;
    constexpr int BUFB   = ABYTES + BBYTES;

    __shared__ __align__(1024) char lds[2 * BUFB];

    const int tid = threadIdx.x;
    const int nwg = gridDim.x;            // always %8==0 here
    const int bid = blockIdx.x;
    const int wgid = (bid & 7) * (nwg >> 3) + (bid >> 3);   // XCD swizzle
    const int bb  = wgid / tilesMN;
    const int rem = wgid % tilesMN;
    const int tm = rem / tilesN, tn = rem % tilesN;
    const int row0 = tm * BM, col0 = tn * 256;

    const h16* Ab = A + (long long)bb * aBatch;
    const h16* Bb = B + (long long)bb * bBatch;

    const int lane = tid & 63, wid = tid >> 6;
    const int wm = wid >> 2, wn = wid & 3;     // 2M x 4N
    const int frow = lane & 15, kq = lane >> 4;

    const int NT = K >> 6;

    f32x4 acc[MF][4];
#pragma unroll
    for (int m = 0; m < MF; ++m)
#pragma unroll
        for (int n = 0; n < 4; ++n) acc[m][n] = (f32x4){0.f, 0.f, 0.f, 0.f};

    char* l0 = (char*)lds;

    auto STAGE_A = [&](int kt, int buf, int mh) {
#pragma unroll
        for (int i = 0; i < ALOADS; ++i) {
            int d = wid * (ALOADS * 64) + i * 64 + lane;
            int s = d & 7, hr = d >> 3;
            int r = ((hr & ~(AH - 1)) << 1) + mh * AH + (hr & (AH - 1));
            int gg = s ^ (r & 7);
            gload16(Ab + (size_t)(row0 + r) * lda + kt + gg * 8,
                    l0 + buf * BUFB + (r * 8 + s) * 16);
        }
    };
    auto STAGE_B = [&](int kt, int buf, int nh) {
#pragma unroll
        for (int i = 0; i < 2; ++i) {
            int d = wid * 128 + i * 64 + lane;
            int s = d & 7, hr = d >> 3;
            int r = ((hr & ~31) << 1) + nh * 32 + (hr & 31);
            int gg = s ^ (r & 7);
            gload16(Bb + (size_t)(col0 + r) * ldb + kt + gg * 8,
                    l0 + buf * BUFB + ABYTES + (r * 8 + s) * 16);
        }
    };
    auto READ_A = [&](int buf, int mh, h16x8 (&af)[MQ][2]) {
#pragma unroll
        for (int mm = 0; mm < MQ; ++mm)
#pragma unroll
            for (int ks = 0; ks < 2; ++ks) {
                int r = wm * WROWS + (mh * MQ + mm) * 16 + frow;
                int s = (ks * 4 + kq) ^ (r & 7);
                af[mm][ks] = *(const h16x8*)(l0 + buf * BUFB + (r * 8 + s) * 16);
            }
    };
    auto READ_B = [&](int buf, int nh, h16x8 (&bf)[2][2]) {
#pragma unroll
        for (int nn = 0; nn < 2; ++nn)
#pragma unroll
            for (int ks = 0; ks < 2; ++ks) {
                int r = wn * 64 + (nh * 2 + nn) * 16 + frow;
                int s = (ks * 4 + kq) ^ (r & 7);
                bf[nn][ks] = *(const h16x8*)(l0 + buf * BUFB + ABYTES + (r * 8 + s) * 16);
            }
    };
    // ks OUTERMOST: 8 independent MFMAs per ks-slice (no adjacent dep pairs)
    auto MFMA_Q = [&](int mh, int nh, h16x8 (&af)[MQ][2], h16x8 (&bf)[2][2]) {
        __builtin_amdgcn_s_setprio(1);
#pragma unroll
        for (int ks = 0; ks < 2; ++ks)
#pragma unroll
            for (int mm = 0; mm < MQ; ++mm)
#pragma unroll
                for (int nn = 0; nn < 2; ++nn)
                    acc[mh * MQ + mm][nh * 2 + nn] =
                        __builtin_amdgcn_mfma_f32_16x16x32_f16(
                            af[mm][ks], bf[nn][ks], acc[mh * MQ + mm][nh * 2 + nn], 0, 0, 0);
        __builtin_amdgcn_s_setprio(0);
    };

    // ---- prologue: K0 fully + K1 {A_mh0, B_nh0, B_nh1} (A_mh1(K1) staged in G0 p0)
    STAGE_A(0, 0, 0); STAGE_B(0, 0, 0); STAGE_B(0, 0, 1); STAGE_A(0, 0, 1);
    STAGE_A(64, 1, 0); STAGE_B(64, 1, 0); STAGE_B(64, 1, 1);
    if constexpr (BM == 256) asm volatile("s_waitcnt vmcnt(6)" ::: "memory");
    else                     asm volatile("s_waitcnt vmcnt(5)" ::: "memory");
    __builtin_amdgcn_s_barrier();

    h16x8 af[MQ][2], bf0[2][2], bf1[2][2];

    for (int G = 0; G < NT; ++G) {
        const int buf = G & 1;
        const int kt1 = (G + 1) << 6, kt2 = (G + 2) << 6;
        // ---- p0: quadrant (0,0); stage A_mh1(G+1)
        READ_A(buf, 0, af);
        READ_B(buf, 0, bf0);
        if (G + 1 < NT) STAGE_A(kt1, buf ^ 1, 1);
        __builtin_amdgcn_s_barrier();
        MFMA_Q(0, 0, af, bf0);
        __builtin_amdgcn_s_barrier();
        // ---- p1: quadrant (0,1); stage A_mh0(G+2)
        READ_B(buf, 1, bf1);
        if (G + 2 < NT) STAGE_A(kt2, buf, 0);
        __builtin_amdgcn_s_barrier();
        MFMA_Q(0, 1, af, bf1);
        __builtin_amdgcn_s_barrier();
        // ---- p2: quadrant (1,0); stage B_nh0(G+2); bf0 reused from p0
        READ_A(buf, 1, af);
        if (G + 2 < NT) STAGE_B(kt2, buf, 0);
        __builtin_amdgcn_s_barrier();
        MFMA_Q(1, 0, af, bf0);
        __builtin_amdgcn_s_barrier();
        // ---- p3: quadrant (1,1); stage B_nh1(G+2); no ds_reads
        if (G + 2 < NT) STAGE_B(kt2, buf, 1);
        __builtin_amdgcn_s_barrier();
        MFMA_Q(1, 1, af, bf1);
        // ---- K-tile boundary: counted vmcnt (never 0 except tail)
        if (G + 2 >= NT) {
            asm volatile("s_waitcnt vmcnt(0)" ::: "memory");
        } else if constexpr (BM == 256) {
            asm volatile("s_waitcnt vmcnt(6)" ::: "memory");
        } else {
            asm volatile("s_waitcnt vmcnt(5)" ::: "memory");
        }
        __builtin_amdgcn_s_barrier();
    }

    // ---- epilogue: C/D layout col=lane&15, row=(lane>>4)*4+j
    const int erow = row0 + wm * WROWS + (lane >> 4) * 4;
    const int ecol = col0 + wn * 64 + (lane & 15);
    if (F32OUT) {
        float* C = (float*)Cv + (long long)bb * cBatch;
#pragma unroll
        for (int m = 0; m < MF; ++m)
#pragma unroll
            for (int n = 0; n < 4; ++n)
#pragma unroll
                for (int j = 0; j < 4; ++j)
                    C[(size_t)(erow + m * 16 + j) * ldc + (ecol + n * 16)] = acc[m][n][j];
    } else {
        h16* C = (h16*)Cv + (long long)bb * cBatch;
#pragma unroll
        for (int m = 0; m < MF; ++m)
#pragma unroll
            for (int n = 0; n < 4; ++n)
#pragma unroll
                for (int j = 0; j < 4; ++j)
                    C[(size_t)(erow + m * 16 + j) * ldc + (ecol + n * 16)] = (h16)acc[m][n][j];
    }
}

// ---- row softmax, in place on fp16 rows of length 2048; one block per row ----
__global__ __launch_bounds__(256) void softmax_rows(h16* __restrict__ buf) {
    const int row = blockIdx.x;
    h16* rp = buf + (size_t)row * 2048;
    const int t = threadIdx.x;
    const int lane = t & 63, wid = t >> 6;

    union { int4 i4; h16 h[8]; } u;
    u.i4 = ((const int4*)rp)[t];
    float f[8];
#pragma unroll
    for (int j = 0; j < 8; ++j) f[j] = (float)u.h[j];

    float m = f[0];
#pragma unroll
    for (int j = 1; j < 8; ++j) m = fmaxf(m, f[j]);
#pragma unroll
    for (int off = 32; off; off >>= 1) m = fmaxf(m, __shfl_xor(m, off));

    __shared__ float smax[4];
    __shared__ float ssum[4];
    if (lane == 0) smax[wid] = m;
    __syncthreads();
    m = fmaxf(fmaxf(smax[0], smax[1]), fmaxf(smax[2], smax[3]));

    float s = 0.f;
#pragma unroll
    for (int j = 0; j < 8; ++j) { f[j] = __expf(f[j] - m); s += f[j]; }
#pragma unroll
    for (int off = 32; off; off >>= 1) s += __shfl_xor(s, off);
    if (lane == 0) ssum[wid] = s;
    __syncthreads();
    float inv = 1.0f / (ssum[0] + ssum[1] + ssum[2] + ssum[3]);

#pragma unroll
    for (int j = 0; j < 8; ++j) u.h[j] = (h16)(f[j] * inv);
    ((int4*)rp)[t] = u.i4;
}

extern "C" void kernel_launch(void* const* d_in, const int* in_sizes, int n_in,
                              void* d_out, int out_size, void* d_ws, size_t ws_size,
                              hipStream_t stream) {
    (void)in_sizes; (void)n_in; (void)out_size; (void)ws_size;
    const float* q = (const float*)d_in[0];
    const float* k = (const float*)d_in[1];
    const float* v = (const float*)d_in[2];
    const float* w = (const float*)d_in[3];
    float* out = (float*)d_out;

    const size_t QKV = (size_t)BB * SS * DD;
    h16* qh = (h16*)d_ws;            // 16 MB (reused as vpT after GEMM1 consumes q)
    h16* kh = qh + QKV;              // 16 MB
    h16* vh = kh + QKV;              // 16 MB
    h16* wh = vh + QKV;              // 2 MB
    h16* sc = wh + (size_t)DD * DD;  // scores / P: 33.5 MB

    // 1) fp32 -> fp16 (scale 1/sqrt(64)=0.125 folded into q)
    cvt_f32_h16<<<(int)(QKV / 8 + 255) / 256, 256, 0, stream>>>(q, qh, (int)(QKV / 8), 0.125f);
    cvt_f32_h16<<<(int)(QKV / 8 + 255) / 256, 256, 0, stream>>>(k, kh, (int)(QKV / 8), 1.0f);
    cvt_f32_h16<<<(int)(QKV / 8 + 255) / 256, 256, 0, stream>>>(v, vh, (int)(QKV / 8), 1.0f);
    cvt_f32_h16<<<(DD * DD / 8 + 255) / 256, 256, 0, stream>>>(w, wh, DD * DD / 8, 1.0f);

    // 2) GEMM1: scores[b][q][k]; M=N=2048, K=1024 per batch. 256x256 tiles:
    //    8x8=64 tiles x 4 batches = 256 wgs (1/CU exact)
    gemm8p<256, false><<<256, 512, 0, stream>>>(
        qh, kh, (void*)sc, DD, DD, SS, DD, /*tilesN=*/8, /*tilesMN=*/64,
        (long long)SS * DD, (long long)SS * DD, (long long)SS * SS);

    // 3) softmax rows in place
    softmax_rows<<<BB * SS, 256, 0, stream>>>(sc);

    // 4) GEMM2: vpT[e][s] = sum_d W[e,d]*V[s,d]; M=1024, N=8192, K=1024.
    //    128x256 tiles: 8x32 = 256 wgs
    h16* vpT = qh;
    gemm8p<128, false><<<256, 512, 0, stream>>>(
        wh, vh, (void*)vpT, DD, DD, BB * SS, DD, /*tilesN=*/32, /*tilesMN=*/256,
        0LL, 0LL, 0LL);

    // 5) GEMM3: Y[b][q][e] = sum_k P[b,q,k]*vpT[e, b*2048+k]; M=2048/batch, N=1024, K=2048.
    //    128x256 tiles: 16x4=64 x 4 batches = 256 wgs
    gemm8p<128, true><<<256, 512, 0, stream>>>(
        sc, vpT, (void*)out, SS, BB * SS, DD, SS, /*tilesN=*/4, /*tilesMN=*/64,
        (long long)SS * SS, (long long)SS, (long long)SS * DD);
}

// Round 5
// 142.060 us; speedup vs baseline: 1.2488x; 1.0491x over previous
//
#include <hip/hip_runtime.h>
#include <hip/hip_fp16.h>
#include <stdint.h>

// ---- types ----
typedef _Float16 h16;
typedef _Float16 h16x8 __attribute__((ext_vector_type(8)));
typedef float f32x4 __attribute__((ext_vector_type(4)));

#define BB 4
#define SS 2048
#define DD 1024

__device__ __forceinline__ void gload16(const void* g, void* l) {
    __builtin_amdgcn_global_load_lds(
        (const __attribute__((address_space(1))) uint32_t*)g,
        (__attribute__((address_space(3))) uint32_t*)l, 16, 0, 0);
}

// ---- fused fp32 -> fp16 convert for q(*0.125), k, v, W in one launch ----
__global__ __launch_bounds__(256) void cvt_all(
    const float* __restrict__ q, const float* __restrict__ k,
    const float* __restrict__ v, const float* __restrict__ w,
    h16* __restrict__ qh, h16* __restrict__ kh,
    h16* __restrict__ vh, h16* __restrict__ wh) {
    const int NQ = (int)((size_t)BB * SS * DD / 8);   // 1048576
    int i = blockIdx.x * 256 + threadIdx.x;
    const float* src; h16* dst; float sc = 1.0f; int j;
    if (i < NQ)            { src = q; dst = qh; sc = 0.125f; j = i; }
    else if (i < 2 * NQ)   { src = k; dst = kh; j = i - NQ; }
    else if (i < 3 * NQ)   { src = v; dst = vh; j = i - 2 * NQ; }
    else                   { src = w; dst = wh; j = i - 3 * NQ;
                             if (j >= DD * DD / 8) return; }
    const float4* p = (const float4*)src + (size_t)j * 2;
    float4 a = p[0], b = p[1];
    union { int4 i4; h16 h[8]; } u;
    u.h[0] = (h16)(a.x * sc); u.h[1] = (h16)(a.y * sc);
    u.h[2] = (h16)(a.z * sc); u.h[3] = (h16)(a.w * sc);
    u.h[4] = (h16)(b.x * sc); u.h[5] = (h16)(b.y * sc);
    u.h[6] = (h16)(b.z * sc); u.h[7] = (h16)(b.w * sc);
    ((int4*)dst)[j] = u.i4;
}

// ==== 2-phase bt-form GEMM: C[m][n] = sum_k A[m][k]*B[n][k] ====
// BN=256 fixed, BM in {256,128}. BK=64, 512 threads = 8 waves (2M x 4N).
// 2 phases per K-tile (m-halves), double-buffered LDS.
// P0: stage FULL tile G+1 (FIFO: B[4], A-h0[AL], A-h1[AL]) + read A-h0 + B-full
//     + MFMA mh0; mid vmcnt(4+2AL)+barrier (drains A-h1(G), staged last iter).
// P1: read A-h1 + MFMA mh1; end vmcnt(AL)+barrier (leaves A-h1(G+1) in flight).
// B-frags live in registers across both phases. Counted vmcnt, never 0 mid-loop.
// T2 granule swizzle: slot s holds global granule s^(r&7) (both-sides, rule 21).
template<int BM, bool F32OUT>
__global__ __launch_bounds__(512, 2) void gemm2p(
    const h16* __restrict__ A, const h16* __restrict__ B, void* __restrict__ Cv,
    int lda, int ldb, int ldc, int K, int tilesN, int tilesMN,
    long long aBatch, long long bBatch, long long cBatch)
{
    constexpr int WROWS  = BM / 2;        // per-wave rows: 128 or 64
    constexpr int MF     = WROWS / 16;    // m-frags per wave: 8 or 4
    constexpr int MH     = MF / 2;        // m-frags per half: 4 or 2
    constexpr int AH     = WROWS / 2;     // A-half run length: 64 or 32
    constexpr int AL     = BM / 128;      // gload instrs per thread per A-half
    constexpr int ABYTES = BM * 128;
    constexpr int BBYTES = 256 * 128;
    constexpr int BUFB   = ABYTES + BBYTES;

    __shared__ __align__(1024) char lds[2 * BUFB];   // 128 KB or 96 KB

    const int tid = threadIdx.x;
    const int nwg = gridDim.x;            // always %8==0 here
    const int bid = blockIdx.x;
    const int wgid = (bid & 7) * (nwg >> 3) + (bid >> 3);   // XCD swizzle
    const int bb  = wgid / tilesMN;
    const int rem = wgid % tilesMN;
    const int tm = rem / tilesN, tn = rem % tilesN;
    const int row0 = tm * BM, col0 = tn * 256;

    const h16* Ab = A + (long long)bb * aBatch;
    const h16* Bb = B + (long long)bb * bBatch;

    const int lane = tid & 63, wid = tid >> 6;
    const int wm = wid >> 2, wn = wid & 3;     // 2M x 4N
    const int frow = lane & 15, kq = lane >> 4;

    const int NT = K >> 6;

    f32x4 acc[MF][4];
#pragma unroll
    for (int m = 0; m < MF; ++m)
#pragma unroll
        for (int n = 0; n < 4; ++n) acc[m][n] = (f32x4){0.f, 0.f, 0.f, 0.f};

    char* l0 = (char*)lds;

    auto STAGE_B = [&](int kt, int buf) {
#pragma unroll
        for (int i = 0; i < 4; ++i) {
            int d = i * 512 + tid;
            int s = d & 7, r = d >> 3;
            int gg = s ^ (r & 7);
            gload16(Bb + (size_t)(col0 + r) * ldb + kt + gg * 8,
                    l0 + buf * BUFB + ABYTES + (r * 8 + s) * 16);
        }
    };
    auto STAGE_AH = [&](int kt, int buf, int mh) {
#pragma unroll
        for (int i = 0; i < AL; ++i) {
            int d = i * 512 + tid;
            int s = d & 7, hr = d >> 3;
            int r = ((hr & ~(AH - 1)) << 1) + mh * AH + (hr & (AH - 1));
            int gg = s ^ (r & 7);
            gload16(Ab + (size_t)(row0 + r) * lda + kt + gg * 8,
                    l0 + buf * BUFB + (r * 8 + s) * 16);
        }
    };
    auto READ_A = [&](int buf, int mh, h16x8 (&af)[MH][2]) {
#pragma unroll
        for (int mm = 0; mm < MH; ++mm)
#pragma unroll
            for (int ks = 0; ks < 2; ++ks) {
                int r = wm * WROWS + (mh * MH + mm) * 16 + frow;
                int s = (ks * 4 + kq) ^ (r & 7);
                af[mm][ks] = *(const h16x8*)(l0 + buf * BUFB + (r * 8 + s) * 16);
            }
    };
    auto READ_B = [&](int buf, h16x8 (&bf)[4][2]) {
#pragma unroll
        for (int nn = 0; nn < 4; ++nn)
#pragma unroll
            for (int ks = 0; ks < 2; ++ks) {
                int r = wn * 64 + nn * 16 + frow;
                int s = (ks * 4 + kq) ^ (r & 7);
                bf[nn][ks] = *(const h16x8*)(l0 + buf * BUFB + ABYTES + (r * 8 + s) * 16);
            }
    };
    auto MFMA_H = [&](int mh, h16x8 (&af)[MH][2], h16x8 (&bf)[4][2]) {
        __builtin_amdgcn_s_setprio(1);
#pragma unroll
        for (int ks = 0; ks < 2; ++ks)
#pragma unroll
            for (int mm = 0; mm < MH; ++mm)
#pragma unroll
                for (int nn = 0; nn < 4; ++nn)
                    acc[mh * MH + mm][nn] =
                        __builtin_amdgcn_mfma_f32_16x16x32_f16(
                            af[mm][ks], bf[nn][ks], acc[mh * MH + mm][nn], 0, 0, 0);
        __builtin_amdgcn_s_setprio(0);
    };

    // ---- prologue: stage tile 0 fully; wait B+A-h0 (leave A-h1(0) in flight)
    STAGE_B(0, 0); STAGE_AH(0, 0, 0); STAGE_AH(0, 0, 1);
    if constexpr (BM == 256) asm volatile("s_waitcnt vmcnt(2)" ::: "memory");
    else                     asm volatile("s_waitcnt vmcnt(1)" ::: "memory");
    __builtin_amdgcn_s_barrier();

    h16x8 af[MH][2], bf[4][2];

    for (int G = 0; G < NT; ++G) {
        const int buf = G & 1;
        const int kt1 = (G + 1) << 6;
        // ---- P0: stage full tile G+1; read A-h0 + B; MFMA mh0
        if (G + 1 < NT) {
            STAGE_B(kt1, buf ^ 1);
            STAGE_AH(kt1, buf ^ 1, 0);
            STAGE_AH(kt1, buf ^ 1, 1);
        }
        READ_A(buf, 0, af);
        READ_B(buf, bf);
        MFMA_H(0, af, bf);
        // mid boundary: drain A-h1(G) (staged last iter); keep tile G+1 in flight
        if (G + 1 < NT) {
            if constexpr (BM == 256) asm volatile("s_waitcnt vmcnt(8)" ::: "memory");
            else                     asm volatile("s_waitcnt vmcnt(6)" ::: "memory");
        } else {
            asm volatile("s_waitcnt vmcnt(0)" ::: "memory");
        }
        __builtin_amdgcn_s_barrier();
        // ---- P1: read A-h1; MFMA mh1
        READ_A(buf, 1, af);
        MFMA_H(1, af, bf);
        if (G + 1 >= NT) break;
        // end boundary: drain B(G+1)+A-h0(G+1); leave A-h1(G+1) in flight
        if constexpr (BM == 256) asm volatile("s_waitcnt vmcnt(2)" ::: "memory");
        else                     asm volatile("s_waitcnt vmcnt(1)" ::: "memory");
        __builtin_amdgcn_s_barrier();
    }

    // ---- epilogue: C/D layout col=lane&15, row=(lane>>4)*4+j
    const int erow = row0 + wm * WROWS + (lane >> 4) * 4;
    const int ecol = col0 + wn * 64 + (lane & 15);
    if (F32OUT) {
        float* C = (float*)Cv + (long long)bb * cBatch;
#pragma unroll
        for (int m = 0; m < MF; ++m)
#pragma unroll
            for (int n = 0; n < 4; ++n)
#pragma unroll
                for (int j = 0; j < 4; ++j)
                    C[(size_t)(erow + m * 16 + j) * ldc + (ecol + n * 16)] = acc[m][n][j];
    } else {
        h16* C = (h16*)Cv + (long long)bb * cBatch;
#pragma unroll
        for (int m = 0; m < MF; ++m)
#pragma unroll
            for (int n = 0; n < 4; ++n)
#pragma unroll
                for (int j = 0; j < 4; ++j)
                    C[(size_t)(erow + m * 16 + j) * ldc + (ecol + n * 16)] = (h16)acc[m][n][j];
    }
}

// ---- row softmax, in place on fp16 rows of length 2048; one block per row ----
__global__ __launch_bounds__(256) void softmax_rows(h16* __restrict__ buf) {
    const int row = blockIdx.x;
    h16* rp = buf + (size_t)row * 2048;
    const int t = threadIdx.x;
    const int lane = t & 63, wid = t >> 6;

    union { int4 i4; h16 h[8]; } u;
    u.i4 = ((const int4*)rp)[t];
    float f[8];
#pragma unroll
    for (int j = 0; j < 8; ++j) f[j] = (float)u.h[j];

    float m = f[0];
#pragma unroll
    for (int j = 1; j < 8; ++j) m = fmaxf(m, f[j]);
#pragma unroll
    for (int off = 32; off; off >>= 1) m = fmaxf(m, __shfl_xor(m, off));

    __shared__ float smax[4];
    __shared__ float ssum[4];
    if (lane == 0) smax[wid] = m;
    __syncthreads();
    m = fmaxf(fmaxf(smax[0], smax[1]), fmaxf(smax[2], smax[3]));

    float s = 0.f;
#pragma unroll
    for (int j = 0; j < 8; ++j) { f[j] = __expf(f[j] - m); s += f[j]; }
#pragma unroll
    for (int off = 32; off; off >>= 1) s += __shfl_xor(s, off);
    if (lane == 0) ssum[wid] = s;
    __syncthreads();
    float inv = 1.0f / (ssum[0] + ssum[1] + ssum[2] + ssum[3]);

#pragma unroll
    for (int j = 0; j < 8; ++j) u.h[j] = (h16)(f[j] * inv);
    ((int4*)rp)[t] = u.i4;
}

extern "C" void kernel_launch(void* const* d_in, const int* in_sizes, int n_in,
                              void* d_out, int out_size, void* d_ws, size_t ws_size,
                              hipStream_t stream) {
    (void)in_sizes; (void)n_in; (void)out_size; (void)ws_size;
    const float* q = (const float*)d_in[0];
    const float* k = (const float*)d_in[1];
    const float* v = (const float*)d_in[2];
    const float* w = (const float*)d_in[3];
    float* out = (float*)d_out;

    const size_t QKV = (size_t)BB * SS * DD;
    h16* qh = (h16*)d_ws;            // 16 MB (reused as vpT after GEMM1 consumes q)
    h16* kh = qh + QKV;              // 16 MB
    h16* vh = kh + QKV;              // 16 MB
    h16* wh = vh + QKV;              // 2 MB
    h16* sc = wh + (size_t)DD * DD;  // scores / P: 33.5 MB

    // 1) fused fp32 -> fp16 (scale 1/sqrt(64)=0.125 folded into q)
    cvt_all<<<12800, 256, 0, stream>>>(q, k, v, w, qh, kh, vh, wh);

    // 2) GEMM1: scores[b][q][k]; M=N=2048, K=1024 per batch. 256x256 tiles:
    //    8x8=64 tiles x 4 batches = 256 wgs (1/CU exact)
    gemm2p<256, false><<<256, 512, 0, stream>>>(
        qh, kh, (void*)sc, DD, DD, SS, DD, /*tilesN=*/8, /*tilesMN=*/64,
        (long long)SS * DD, (long long)SS * DD, (long long)SS * SS);

    // 3) softmax rows in place
    softmax_rows<<<BB * SS, 256, 0, stream>>>(sc);

    // 4) GEMM2: vpT[e][s] = sum_d W[e,d]*V[s,d]; M=1024, N=8192, K=1024.
    //    128x256 tiles: 8x32 = 256 wgs
    h16* vpT = qh;
    gemm2p<128, false><<<256, 512, 0, stream>>>(
        wh, vh, (void*)vpT, DD, DD, BB * SS, DD, /*tilesN=*/32, /*tilesMN=*/256,
        0LL, 0LL, 0LL);

    // 5) GEMM3: Y[b][q][e] = sum_k P[b,q,k]*vpT[e, b*2048+k]; M=2048/batch, N=1024, K=2048.
    //    128x256 tiles: 16x4=64 x 4 batches = 256 wgs
    gemm2p<128, true><<<256, 512, 0, stream>>>(
        sc, vpT, (void*)out, SS, BB * SS, DD, SS, /*tilesN=*/4, /*tilesMN=*/64,
        (long long)SS * SS, (long long)SS, (long long)SS * DD);
}

// Round 6
// 141.259 us; speedup vs baseline: 1.2559x; 1.0057x over previous
//
#include <hip/hip_runtime.h>
#include <hip/hip_fp16.h>
#include <stdint.h>

// ---- types ----
typedef _Float16 h16;
typedef _Float16 h16x8 __attribute__((ext_vector_type(8)));
typedef float f32x4 __attribute__((ext_vector_type(4)));

#define BB 4
#define SS 2048
#define DD 1024

__device__ __forceinline__ void gload16(const void* g, void* l) {
    __builtin_amdgcn_global_load_lds(
        (const __attribute__((address_space(1))) uint32_t*)g,
        (__attribute__((address_space(3))) uint32_t*)l, 16, 0, 0);
}

// ---- fused fp32 -> fp16 convert for q(*0.125), k, v, W in one launch ----
__global__ __launch_bounds__(256) void cvt_all(
    const float* __restrict__ q, const float* __restrict__ k,
    const float* __restrict__ v, const float* __restrict__ w,
    h16* __restrict__ qh, h16* __restrict__ kh,
    h16* __restrict__ vh, h16* __restrict__ wh) {
    const int NQ = (int)((size_t)BB * SS * DD / 8);   // 1048576
    int i = blockIdx.x * 256 + threadIdx.x;
    const float* src; h16* dst; float sc = 1.0f; int j;
    if (i < NQ)            { src = q; dst = qh; sc = 0.125f; j = i; }
    else if (i < 2 * NQ)   { src = k; dst = kh; j = i - NQ; }
    else if (i < 3 * NQ)   { src = v; dst = vh; j = i - 2 * NQ; }
    else                   { src = w; dst = wh; j = i - 3 * NQ;
                             if (j >= DD * DD / 8) return; }
    const float4* p = (const float4*)src + (size_t)j * 2;
    float4 a = p[0], b = p[1];
    union { int4 i4; h16 h[8]; } u;
    u.h[0] = (h16)(a.x * sc); u.h[1] = (h16)(a.y * sc);
    u.h[2] = (h16)(a.z * sc); u.h[3] = (h16)(a.w * sc);
    u.h[4] = (h16)(b.x * sc); u.h[5] = (h16)(b.y * sc);
    u.h[6] = (h16)(b.z * sc); u.h[7] = (h16)(b.w * sc);
    ((int4*)dst)[j] = u.i4;
}

// ==== CONTROL: 2-phase bt-form GEMM, BM=256/BN=256, 8 waves, 1 block/CU ====
// (round-5 kernel, unchanged; used for GEMM1)
template<int BM, bool F32OUT>
__global__ __launch_bounds__(512, 2) void gemm2p(
    const h16* __restrict__ A, const h16* __restrict__ B, void* __restrict__ Cv,
    int lda, int ldb, int ldc, int K, int tilesN, int tilesMN,
    long long aBatch, long long bBatch, long long cBatch)
{
    constexpr int WROWS  = BM / 2;
    constexpr int MF     = WROWS / 16;
    constexpr int MH     = MF / 2;
    constexpr int AH     = WROWS / 2;
    constexpr int AL     = BM / 128;
    constexpr int ABYTES = BM * 128;
    constexpr int BBYTES = 256 * 128;
    constexpr int BUFB   = ABYTES + BBYTES;

    __shared__ __align__(1024) char lds[2 * BUFB];

    const int tid = threadIdx.x;
    const int nwg = gridDim.x;
    const int bid = blockIdx.x;
    const int wgid = (bid & 7) * (nwg >> 3) + (bid >> 3);
    const int bb  = wgid / tilesMN;
    const int rem = wgid % tilesMN;
    const int tm = rem / tilesN, tn = rem % tilesN;
    const int row0 = tm * BM, col0 = tn * 256;

    const h16* Ab = A + (long long)bb * aBatch;
    const h16* Bb = B + (long long)bb * bBatch;

    const int lane = tid & 63, wid = tid >> 6;
    const int wm = wid >> 2, wn = wid & 3;
    const int frow = lane & 15, kq = lane >> 4;

    const int NT = K >> 6;

    f32x4 acc[MF][4];
#pragma unroll
    for (int m = 0; m < MF; ++m)
#pragma unroll
        for (int n = 0; n < 4; ++n) acc[m][n] = (f32x4){0.f, 0.f, 0.f, 0.f};

    char* l0 = (char*)lds;

    auto STAGE_B = [&](int kt, int buf) {
#pragma unroll
        for (int i = 0; i < 4; ++i) {
            int d = i * 512 + tid;
            int s = d & 7, r = d >> 3;
            int gg = s ^ (r & 7);
            gload16(Bb + (size_t)(col0 + r) * ldb + kt + gg * 8,
                    l0 + buf * BUFB + ABYTES + (r * 8 + s) * 16);
        }
    };
    auto STAGE_AH = [&](int kt, int buf, int mh) {
#pragma unroll
        for (int i = 0; i < AL; ++i) {
            int d = i * 512 + tid;
            int s = d & 7, hr = d >> 3;
            int r = ((hr & ~(AH - 1)) << 1) + mh * AH + (hr & (AH - 1));
            int gg = s ^ (r & 7);
            gload16(Ab + (size_t)(row0 + r) * lda + kt + gg * 8,
                    l0 + buf * BUFB + (r * 8 + s) * 16);
        }
    };
    auto READ_A = [&](int buf, int mh, h16x8 (&af)[MH][2]) {
#pragma unroll
        for (int mm = 0; mm < MH; ++mm)
#pragma unroll
            for (int ks = 0; ks < 2; ++ks) {
                int r = wm * WROWS + (mh * MH + mm) * 16 + frow;
                int s = (ks * 4 + kq) ^ (r & 7);
                af[mm][ks] = *(const h16x8*)(l0 + buf * BUFB + (r * 8 + s) * 16);
            }
    };
    auto READ_B = [&](int buf, h16x8 (&bf)[4][2]) {
#pragma unroll
        for (int nn = 0; nn < 4; ++nn)
#pragma unroll
            for (int ks = 0; ks < 2; ++ks) {
                int r = wn * 64 + nn * 16 + frow;
                int s = (ks * 4 + kq) ^ (r & 7);
                bf[nn][ks] = *(const h16x8*)(l0 + buf * BUFB + ABYTES + (r * 8 + s) * 16);
            }
    };
    auto MFMA_H = [&](int mh, h16x8 (&af)[MH][2], h16x8 (&bf)[4][2]) {
        __builtin_amdgcn_s_setprio(1);
#pragma unroll
        for (int ks = 0; ks < 2; ++ks)
#pragma unroll
            for (int mm = 0; mm < MH; ++mm)
#pragma unroll
                for (int nn = 0; nn < 4; ++nn)
                    acc[mh * MH + mm][nn] =
                        __builtin_amdgcn_mfma_f32_16x16x32_f16(
                            af[mm][ks], bf[nn][ks], acc[mh * MH + mm][nn], 0, 0, 0);
        __builtin_amdgcn_s_setprio(0);
    };

    STAGE_B(0, 0); STAGE_AH(0, 0, 0); STAGE_AH(0, 0, 1);
    if constexpr (BM == 256) asm volatile("s_waitcnt vmcnt(2)" ::: "memory");
    else                     asm volatile("s_waitcnt vmcnt(1)" ::: "memory");
    __builtin_amdgcn_s_barrier();

    h16x8 af[MH][2], bf[4][2];

    for (int G = 0; G < NT; ++G) {
        const int buf = G & 1;
        const int kt1 = (G + 1) << 6;
        if (G + 1 < NT) {
            STAGE_B(kt1, buf ^ 1);
            STAGE_AH(kt1, buf ^ 1, 0);
            STAGE_AH(kt1, buf ^ 1, 1);
        }
        READ_A(buf, 0, af);
        READ_B(buf, bf);
        MFMA_H(0, af, bf);
        if (G + 1 < NT) {
            if constexpr (BM == 256) asm volatile("s_waitcnt vmcnt(8)" ::: "memory");
            else                     asm volatile("s_waitcnt vmcnt(6)" ::: "memory");
        } else {
            asm volatile("s_waitcnt vmcnt(0)" ::: "memory");
        }
        __builtin_amdgcn_s_barrier();
        READ_A(buf, 1, af);
        MFMA_H(1, af, bf);
        if (G + 1 >= NT) break;
        if constexpr (BM == 256) asm volatile("s_waitcnt vmcnt(2)" ::: "memory");
        else                     asm volatile("s_waitcnt vmcnt(1)" ::: "memory");
        __builtin_amdgcn_s_barrier();
    }

    const int erow = row0 + wm * WROWS + (lane >> 4) * 4;
    const int ecol = col0 + wn * 64 + (lane & 15);
    if (F32OUT) {
        float* C = (float*)Cv + (long long)bb * cBatch;
#pragma unroll
        for (int m = 0; m < MF; ++m)
#pragma unroll
            for (int n = 0; n < 4; ++n)
#pragma unroll
                for (int j = 0; j < 4; ++j)
                    C[(size_t)(erow + m * 16 + j) * ldc + (ecol + n * 16)] = acc[m][n][j];
    } else {
        h16* C = (h16*)Cv + (long long)bb * cBatch;
#pragma unroll
        for (int m = 0; m < MF; ++m)
#pragma unroll
            for (int n = 0; n < 4; ++n)
#pragma unroll
                for (int j = 0; j < 4; ++j)
                    C[(size_t)(erow + m * 16 + j) * ldc + (ecol + n * 16)] = (h16)acc[m][n][j];
    }
}

// ==== TREATMENT: 128x128 tile, 4 waves (2Mx2N), 256 thr, 64KB LDS ====
// -> 2 independent blocks/CU (m114 desync: one block MFMAs while the
// other sits at its boundary wait). Same 2-phase counted-vmcnt ledger:
// stage 8 loads/K-tile (B:4, A-h0:2, A-h1:2); mid vmcnt(8), end vmcnt(2).
template<bool F32OUT>
__global__ __launch_bounds__(256, 2) void gemm2p_sm(
    const h16* __restrict__ A, const h16* __restrict__ B, void* __restrict__ Cv,
    int lda, int ldb, int ldc, int K, int tilesN, int tilesMN,
    long long aBatch, long long bBatch, long long cBatch)
{
    constexpr int ABYTES = 128 * 128;   // 16 KB
    constexpr int BBYTES = 128 * 128;   // 16 KB
    constexpr int BUFB   = ABYTES + BBYTES;

    __shared__ __align__(1024) char lds[2 * BUFB];   // 64 KB -> 2 blocks/CU

    const int tid = threadIdx.x;
    const int nwg = gridDim.x;
    const int bid = blockIdx.x;
    const int wgid = (bid & 7) * (nwg >> 3) + (bid >> 3);   // XCD swizzle
    const int bb  = wgid / tilesMN;
    const int rem = wgid % tilesMN;
    const int tm = rem / tilesN, tn = rem % tilesN;
    const int row0 = tm * 128, col0 = tn * 128;

    const h16* Ab = A + (long long)bb * aBatch;
    const h16* Bb = B + (long long)bb * bBatch;

    const int lane = tid & 63, wid = tid >> 6;
    const int wm = wid >> 1, wn = wid & 1;     // 2M x 2N, wave tile 64x64
    const int frow = lane & 15, kq = lane >> 4;

    const int NT = K >> 6;

    f32x4 acc[4][4];
#pragma unroll
    for (int m = 0; m < 4; ++m)
#pragma unroll
        for (int n = 0; n < 4; ++n) acc[m][n] = (f32x4){0.f, 0.f, 0.f, 0.f};

    char* l0 = (char*)lds;

    auto STAGE_B = [&](int kt, int buf) {
#pragma unroll
        for (int i = 0; i < 4; ++i) {
            int d = i * 256 + tid;
            int s = d & 7, r = d >> 3;
            int gg = s ^ (r & 7);
            gload16(Bb + (size_t)(col0 + r) * ldb + kt + gg * 8,
                    l0 + buf * BUFB + ABYTES + (r * 8 + s) * 16);
        }
    };
    auto STAGE_AH = [&](int kt, int buf, int mh) {
#pragma unroll
        for (int i = 0; i < 2; ++i) {
            int d = i * 256 + tid;
            int s = d & 7, hr = d >> 3;
            int r = ((hr & ~31) << 1) + mh * 32 + (hr & 31);
            int gg = s ^ (r & 7);
            gload16(Ab + (size_t)(row0 + r) * lda + kt + gg * 8,
                    l0 + buf * BUFB + (r * 8 + s) * 16);
        }
    };
    auto READ_A = [&](int buf, int mh, h16x8 (&af)[2][2]) {
#pragma unroll
        for (int mm = 0; mm < 2; ++mm)
#pragma unroll
            for (int ks = 0; ks < 2; ++ks) {
                int r = wm * 64 + (mh * 2 + mm) * 16 + frow;
                int s = (ks * 4 + kq) ^ (r & 7);
                af[mm][ks] = *(const h16x8*)(l0 + buf * BUFB + (r * 8 + s) * 16);
            }
    };
    auto READ_B = [&](int buf, h16x8 (&bf)[4][2]) {
#pragma unroll
        for (int nn = 0; nn < 4; ++nn)
#pragma unroll
            for (int ks = 0; ks < 2; ++ks) {
                int r = wn * 64 + nn * 16 + frow;
                int s = (ks * 4 + kq) ^ (r & 7);
                bf[nn][ks] = *(const h16x8*)(l0 + buf * BUFB + ABYTES + (r * 8 + s) * 16);
            }
    };
    auto MFMA_H = [&](int mh, h16x8 (&af)[2][2], h16x8 (&bf)[4][2]) {
        __builtin_amdgcn_s_setprio(1);
#pragma unroll
        for (int ks = 0; ks < 2; ++ks)
#pragma unroll
            for (int mm = 0; mm < 2; ++mm)
#pragma unroll
                for (int nn = 0; nn < 4; ++nn)
                    acc[mh * 2 + mm][nn] =
                        __builtin_amdgcn_mfma_f32_16x16x32_f16(
                            af[mm][ks], bf[nn][ks], acc[mh * 2 + mm][nn], 0, 0, 0);
        __builtin_amdgcn_s_setprio(0);
    };

    // prologue: stage tile 0; drain B+A-h0 (leave A-h1(0): 2 loads in flight)
    STAGE_B(0, 0); STAGE_AH(0, 0, 0); STAGE_AH(0, 0, 1);
    asm volatile("s_waitcnt vmcnt(2)" ::: "memory");
    __builtin_amdgcn_s_barrier();

    h16x8 af[2][2], bf[4][2];

    for (int G = 0; G < NT; ++G) {
        const int buf = G & 1;
        const int kt1 = (G + 1) << 6;
        // P0: stage full tile G+1; read A-h0 + B; MFMA mh0
        if (G + 1 < NT) {
            STAGE_B(kt1, buf ^ 1);
            STAGE_AH(kt1, buf ^ 1, 0);
            STAGE_AH(kt1, buf ^ 1, 1);
        }
        READ_A(buf, 0, af);
        READ_B(buf, bf);
        MFMA_H(0, af, bf);
        // mid: drain A-h1(G) (staged last iter); keep tile G+1 (8 loads) in flight
        if (G + 1 < NT) asm volatile("s_waitcnt vmcnt(8)" ::: "memory");
        else            asm volatile("s_waitcnt vmcnt(0)" ::: "memory");
        __builtin_amdgcn_s_barrier();
        // P1: read A-h1; MFMA mh1
        READ_A(buf, 1, af);
        MFMA_H(1, af, bf);
        if (G + 1 >= NT) break;
        // end: drain B(G+1)+A-h0(G+1); leave A-h1(G+1) (2 loads) in flight
        asm volatile("s_waitcnt vmcnt(2)" ::: "memory");
        __builtin_amdgcn_s_barrier();
    }

    const int erow = row0 + wm * 64 + (lane >> 4) * 4;
    const int ecol = col0 + wn * 64 + (lane & 15);
    if (F32OUT) {
        float* C = (float*)Cv + (long long)bb * cBatch;
#pragma unroll
        for (int m = 0; m < 4; ++m)
#pragma unroll
            for (int n = 0; n < 4; ++n)
#pragma unroll
                for (int j = 0; j < 4; ++j)
                    C[(size_t)(erow + m * 16 + j) * ldc + (ecol + n * 16)] = acc[m][n][j];
    } else {
        h16* C = (h16*)Cv + (long long)bb * cBatch;
#pragma unroll
        for (int m = 0; m < 4; ++m)
#pragma unroll
            for (int n = 0; n < 4; ++n)
#pragma unroll
                for (int j = 0; j < 4; ++j)
                    C[(size_t)(erow + m * 16 + j) * ldc + (ecol + n * 16)] = (h16)acc[m][n][j];
    }
}

// ---- row softmax, in place on fp16 rows of length 2048; one block per row ----
__global__ __launch_bounds__(256) void softmax_rows(h16* __restrict__ buf) {
    const int row = blockIdx.x;
    h16* rp = buf + (size_t)row * 2048;
    const int t = threadIdx.x;
    const int lane = t & 63, wid = t >> 6;

    union { int4 i4; h16 h[8]; } u;
    u.i4 = ((const int4*)rp)[t];
    float f[8];
#pragma unroll
    for (int j = 0; j < 8; ++j) f[j] = (float)u.h[j];

    float m = f[0];
#pragma unroll
    for (int j = 1; j < 8; ++j) m = fmaxf(m, f[j]);
#pragma unroll
    for (int off = 32; off; off >>= 1) m = fmaxf(m, __shfl_xor(m, off));

    __shared__ float smax[4];
    __shared__ float ssum[4];
    if (lane == 0) smax[wid] = m;
    __syncthreads();
    m = fmaxf(fmaxf(smax[0], smax[1]), fmaxf(smax[2], smax[3]));

    float s = 0.f;
#pragma unroll
    for (int j = 0; j < 8; ++j) { f[j] = __expf(f[j] - m); s += f[j]; }
#pragma unroll
    for (int off = 32; off; off >>= 1) s += __shfl_xor(s, off);
    if (lane == 0) ssum[wid] = s;
    __syncthreads();
    float inv = 1.0f / (ssum[0] + ssum[1] + ssum[2] + ssum[3]);

#pragma unroll
    for (int j = 0; j < 8; ++j) u.h[j] = (h16)(f[j] * inv);
    ((int4*)rp)[t] = u.i4;
}

extern "C" void kernel_launch(void* const* d_in, const int* in_sizes, int n_in,
                              void* d_out, int out_size, void* d_ws, size_t ws_size,
                              hipStream_t stream) {
    (void)in_sizes; (void)n_in; (void)out_size; (void)ws_size;
    const float* q = (const float*)d_in[0];
    const float* k = (const float*)d_in[1];
    const float* v = (const float*)d_in[2];
    const float* w = (const float*)d_in[3];
    float* out = (float*)d_out;

    const size_t QKV = (size_t)BB * SS * DD;
    h16* qh = (h16*)d_ws;            // 16 MB (reused as vpT after GEMM1 consumes q)
    h16* kh = qh + QKV;              // 16 MB
    h16* vh = kh + QKV;              // 16 MB
    h16* wh = vh + QKV;              // 2 MB
    h16* sc = wh + (size_t)DD * DD;  // scores / P: 33.5 MB

    // 1) fused fp32 -> fp16 (scale 1/sqrt(64)=0.125 folded into q)
    cvt_all<<<12800, 256, 0, stream>>>(q, k, v, w, qh, kh, vh, wh);

    // 2) GEMM1 (CONTROL, unchanged): scores[b][q][k]; 256x256 tiles, 256 wgs
    gemm2p<256, false><<<256, 512, 0, stream>>>(
        qh, kh, (void*)sc, DD, DD, SS, DD, /*tilesN=*/8, /*tilesMN=*/64,
        (long long)SS * DD, (long long)SS * DD, (long long)SS * SS);

    // 3) softmax rows in place
    softmax_rows<<<BB * SS, 256, 0, stream>>>(sc);

    // 4) GEMM2 (TREATMENT): vpT[e][s] = sum_d W[e,d]*V[s,d]; M=1024, N=8192, K=1024.
    //    128x128 tiles: 8x64 = 512 wgs, 2 blocks/CU
    h16* vpT = qh;
    gemm2p_sm<false><<<512, 256, 0, stream>>>(
        wh, vh, (void*)vpT, DD, DD, BB * SS, DD, /*tilesN=*/64, /*tilesMN=*/512,
        0LL, 0LL, 0LL);

    // 5) GEMM3 (TREATMENT): Y[b][q][e] = sum_k P[b,q,k]*vpT[e, b*2048+k];
    //    M=2048/batch, N=1024, K=2048. 128x128 tiles: 16x8=128 x 4 batches = 512 wgs
    gemm2p_sm<true><<<512, 256, 0, stream>>>(
        sc, vpT, (void*)out, SS, BB * SS, DD, SS, /*tilesN=*/8, /*tilesMN=*/128,
        (long long)SS * SS, (long long)SS, (long long)SS * DD);
}